// Round 1
// baseline (1052.505 us; speedup 1.0000x reference)
//
#include <hip/hip_runtime.h>
#include <math.h>

#define BB 8
#define TT 2048
#define NE 1024
#define HH 64
#define BT (BB * TT)

// ---------------------------------------------------------------------------
// Kernel 1: QKV projection.  One block (256 thr) per token row.
//   - stage x[row][0:1024] (4 KB) in LDS via float4 (256 * 16B)
//   - threads 0..63 -> Q, 64..127 -> K, 128..191 -> V  (wave-aligned so each
//     wave streams one weight matrix; W column reads are coalesced: 64
//     consecutive floats per wave per n)
// ---------------------------------------------------------------------------
__global__ __launch_bounds__(256) void qkv_proj_kernel(
    const float* __restrict__ x,
    const float* __restrict__ Wk,
    const float* __restrict__ Wq,
    const float* __restrict__ Wv,
    float* __restrict__ Q, float* __restrict__ K, float* __restrict__ V) {
  __shared__ float xs[NE];
  const int row = blockIdx.x;  // 0..BT-1
  const int tid = threadIdx.x;

  const float4* xrow = reinterpret_cast<const float4*>(x + (size_t)row * NE);
  reinterpret_cast<float4*>(xs)[tid] = xrow[tid];  // 256*4 = 1024 floats
  __syncthreads();

  if (tid < 192) {
    const int which = tid >> 6;  // 0=Q wave, 1=K wave, 2=V wave
    const int h = tid & 63;
    const float* __restrict__ W = (which == 0) ? Wq : (which == 1) ? Wk : Wv;
    float acc = 0.f;
#pragma unroll 8
    for (int n = 0; n < NE; ++n) {
      acc = fmaf(xs[n], W[n * HH + h], acc);
    }
    float* __restrict__ dst = (which == 0) ? Q : (which == 1) ? K : V;
    dst[(size_t)row * HH + h] = acc;
  }
}

// ---------------------------------------------------------------------------
// Kernel 2: causal attention for one (b, q) row per block (256 thr, 4 waves).
//   phase 1: scores sc[k] = 0.125 * dot(Q[q], K[k]) for k <= q (strided by 256)
//   phase 2: block max reduce, exp, block sum reduce
//   phase 3: PV — group g=tid>>6 strides k by 4; lane h=tid&63 gives coalesced
//            V reads; 4 partials combined in LDS; divide by denom, store.
// ---------------------------------------------------------------------------
__global__ __launch_bounds__(256) void attn_kernel(
    const float* __restrict__ Q, const float* __restrict__ K,
    const float* __restrict__ V, float* __restrict__ out) {
  __shared__ float sc[TT];      // 8 KB score row
  __shared__ float qs[HH];
  __shared__ float red[8];
  __shared__ float pv[4][HH];

  const int blk = blockIdx.x;
  const int b = blk >> 11;      // / TT
  const int q = blk & (TT - 1);
  const int tid = threadIdx.x;
  const size_t base = (size_t)b * TT * HH;

  if (tid < HH) qs[tid] = Q[base + (size_t)q * HH + tid];
  __syncthreads();

  // q vector into registers (16 float4 = 64 VGPRs, phase-1 only)
  float4 qreg[16];
  const float4* qv4 = reinterpret_cast<const float4*>(qs);
#pragma unroll
  for (int i = 0; i < 16; ++i) qreg[i] = qv4[i];

  const int n = q + 1;  // causal length
  float m_local = -INFINITY;
  for (int k = tid; k < n; k += 256) {
    const float4* kr = reinterpret_cast<const float4*>(K + base + (size_t)k * HH);
    float acc = 0.f;
#pragma unroll
    for (int i = 0; i < 16; ++i) {
      const float4 kv = kr[i];
      acc = fmaf(qreg[i].x, kv.x, acc);
      acc = fmaf(qreg[i].y, kv.y, acc);
      acc = fmaf(qreg[i].z, kv.z, acc);
      acc = fmaf(qreg[i].w, kv.w, acc);
    }
    acc *= 0.125f;  // 1/sqrt(64)
    sc[k] = acc;
    m_local = fmaxf(m_local, acc);
  }

  // block max reduce (wave shuffle + LDS across 4 waves)
#pragma unroll
  for (int off = 32; off > 0; off >>= 1)
    m_local = fmaxf(m_local, __shfl_xor(m_local, off));
  if ((tid & 63) == 0) red[tid >> 6] = m_local;
  __syncthreads();
  const float m = fmaxf(fmaxf(red[0], red[1]), fmaxf(red[2], red[3]));

  // exp + sum
  float s_local = 0.f;
  for (int k = tid; k < n; k += 256) {
    const float p = __expf(sc[k] - m);
    sc[k] = p;
    s_local += p;
  }
#pragma unroll
  for (int off = 32; off > 0; off >>= 1)
    s_local += __shfl_xor(s_local, off);
  if ((tid & 63) == 0) red[4 + (tid >> 6)] = s_local;
  __syncthreads();  // also publishes sc[] p-values for PV
  const float denom = red[4] + red[5] + red[6] + red[7];

  // PV
  const int g = tid >> 6;
  const int h = tid & 63;
  float acc = 0.f;
#pragma unroll 4
  for (int k = g; k < n; k += 4) {
    acc = fmaf(sc[k], V[base + (size_t)k * HH + h], acc);
  }
  pv[g][h] = acc;
  __syncthreads();
  if (tid < HH) {
    const float r = (pv[0][tid] + pv[1][tid] + pv[2][tid] + pv[3][tid]) / denom;
    out[base + (size_t)q * HH + tid] = r;
  }
}

extern "C" void kernel_launch(void* const* d_in, const int* in_sizes, int n_in,
                              void* d_out, int out_size, void* d_ws, size_t ws_size,
                              hipStream_t stream) {
  const float* x  = (const float*)d_in[0];
  const float* Wk = (const float*)d_in[1];
  const float* Wq = (const float*)d_in[2];
  const float* Wv = (const float*)d_in[3];
  float* out = (float*)d_out;

  float* ws = (float*)d_ws;
  float* Q = ws;
  float* K = ws + (size_t)BT * HH;
  float* V = ws + 2 * (size_t)BT * HH;

  qkv_proj_kernel<<<BT, 256, 0, stream>>>(x, Wk, Wq, Wv, Q, K, V);
  attn_kernel<<<BT, 256, 0, stream>>>(Q, K, V, out);
}

// Round 2
// 235.364 us; speedup vs baseline: 4.4718x; 4.4718x over previous
//
#include <hip/hip_runtime.h>
#include <math.h>

#define BB 8
#define TT 2048
#define NE 1024
#define HH 64
#define BT (BB * TT)

typedef __attribute__((ext_vector_type(8))) short s8v;   // 8 x bf16 fragment
typedef __attribute__((ext_vector_type(4))) float f4v;   // 4 x f32 accum

__device__ inline unsigned short f2bf(float f) {
  union { float f; unsigned u; } v;
  v.f = f;
  unsigned r = (v.u + 0x7FFFu + ((v.u >> 16) & 1u)) >> 16;  // RNE
  return (unsigned short)r;
}

// ---------------------------------------------------------------------------
// Kernel 0: W [1024][64] f32 x3  ->  W^T [3][64][1024] bf16
// ---------------------------------------------------------------------------
__global__ __launch_bounds__(256) void conv_wt_kernel(
    const float* __restrict__ Wq, const float* __restrict__ Wk,
    const float* __restrict__ Wv, unsigned short* __restrict__ WT) {
  const int idx = blockIdx.x * 256 + threadIdx.x;  // 0..3*65536-1
  const int m = idx >> 16;
  const int e = idx & 65535;
  const int n = e >> 6;
  const int h = e & 63;
  const float* W = (m == 0) ? Wq : (m == 1) ? Wk : Wv;
  WT[(size_t)m * 65536 + (size_t)h * NE + n] = f2bf(W[e]);
}

// ---------------------------------------------------------------------------
// Kernel 1: QKV projection via MFMA.  Block: 256 thr (4 waves), 64 rows.
//   acc[n]: n=0..3 -> Q cols, 4..7 -> K cols, 8..11 -> V cols (16 cols each).
//   x staged f32->bf16 in LDS [64][72] (pad 8 -> 2-way-max bank aliasing).
//   Q,K stored bf16 row-major [BT][64]; V stored transposed [B][64][T] bf16.
// ---------------------------------------------------------------------------
__global__ __launch_bounds__(256) void qkv_proj_mfma(
    const float* __restrict__ x, const unsigned short* __restrict__ WT,
    unsigned short* __restrict__ Q, unsigned short* __restrict__ K,
    unsigned short* __restrict__ VT) {
  __shared__ unsigned short xs[64][72];
  const int tid = threadIdx.x;
  const int lane = tid & 63;
  const int w = tid >> 6;
  const int row0 = blockIdx.x * 64;
  const int lr = lane & 15;   // M-row (A) / N-col (B) within 16
  const int lg = lane >> 4;   // k-group

  f4v acc[12];
#pragma unroll
  for (int n = 0; n < 12; ++n) acc[n] = (f4v)0.f;

  for (int kc = 0; kc < NE; kc += 64) {
    __syncthreads();
    {  // stage x[row0..+63][kc..+63] -> bf16 LDS, coalesced 256B/16-lane-group
      const int c4 = (tid & 15) * 4;
      const int rbase = tid >> 4;
#pragma unroll
      for (int i = 0; i < 4; ++i) {
        const int r = rbase + 16 * i;
        const float4 v = *reinterpret_cast<const float4*>(
            x + (size_t)(row0 + r) * NE + kc + c4);
        ushort4 o;
        o.x = f2bf(v.x); o.y = f2bf(v.y); o.z = f2bf(v.z); o.w = f2bf(v.w);
        *reinterpret_cast<ushort4*>(&xs[r][c4]) = o;
      }
    }
    __syncthreads();
#pragma unroll
    for (int ks = 0; ks < 64; ks += 32) {
      const int ar = w * 16 + lr;
      const int ac = ks + lg * 8;
      const ushort4 lo = *reinterpret_cast<const ushort4*>(&xs[ar][ac]);
      const ushort4 hi = *reinterpret_cast<const ushort4*>(&xs[ar][ac + 4]);
      s8v a;
      a[0] = lo.x; a[1] = lo.y; a[2] = lo.z; a[3] = lo.w;
      a[4] = hi.x; a[5] = hi.y; a[6] = hi.z; a[7] = hi.w;
#pragma unroll
      for (int n = 0; n < 12; ++n) {
        const int m = n >> 2;
        const int col0 = (n & 3) * 16;
        const s8v b = *reinterpret_cast<const s8v*>(
            WT + (size_t)m * 65536 + (size_t)(col0 + lr) * NE + kc + ks + lg * 8);
        acc[n] = __builtin_amdgcn_mfma_f32_16x16x32_bf16(a, b, acc[n], 0, 0, 0);
      }
    }
  }
#pragma unroll
  for (int n = 0; n < 12; ++n) {
    const int m = n >> 2;
    const int col = (n & 3) * 16 + lr;
#pragma unroll
    for (int r = 0; r < 4; ++r) {
      const int rr = row0 + w * 16 + lg * 4 + r;  // D: row=(lane>>4)*4+reg
      const unsigned short bv = f2bf(acc[n][r]);
      if (m == 0) {
        Q[(size_t)rr * HH + col] = bv;
      } else if (m == 1) {
        K[(size_t)rr * HH + col] = bv;
      } else {
        const int bb = rr >> 11, t = rr & (TT - 1);
        VT[((size_t)bb * HH + col) * TT + t] = bv;
      }
    }
  }
}

// ---------------------------------------------------------------------------
// Kernel 2: causal flash attention, MFMA 16x16x32 bf16.
//   Block: 4 waves; wave w owns q rows [qb*64 + w*16, +16).  k-tiles of 64.
//   batch = blockIdx & 7  (XCD-affinity: each batch's K/V stays in one L2).
//   S/D layout: row q = (lane>>4)*4+reg, col k = lane&15  (per 16-wide tile).
//   P goes D-layout -> LDS [16][72] -> A-layout frags for PV.
// ---------------------------------------------------------------------------
__global__ __launch_bounds__(256) void flash_attn_mfma(
    const unsigned short* __restrict__ Q, const unsigned short* __restrict__ K,
    const unsigned short* __restrict__ VT, float* __restrict__ out) {
  __shared__ unsigned short pl[4][16][72];
  const int tid = threadIdx.x;
  const int lane = tid & 63;
  const int w = tid >> 6;
  const int lr = lane & 15;
  const int lg = lane >> 4;
  const int bid = blockIdx.x;
  const int b = bid & 7;        // batch -> XCD affinity
  const int qb = bid >> 3;      // 0..31 q-block of 64 rows
  const int q0w = qb * 64 + w * 16;
  const size_t rowbase = (size_t)b * TT;

  s8v qf[2];
#pragma unroll
  for (int dh = 0; dh < 2; ++dh)
    qf[dh] = *reinterpret_cast<const s8v*>(
        Q + (rowbase + q0w + lr) * HH + dh * 32 + lg * 8);

  f4v o[4];
#pragma unroll
  for (int n = 0; n < 4; ++n) o[n] = (f4v)0.f;
  float mrow[4], lrow[4];
#pragma unroll
  for (int r = 0; r < 4; ++r) { mrow[r] = -INFINITY; lrow[r] = 0.f; }

  const int nt = qb + 1;  // uniform across the block's waves
  for (int kt = 0; kt < nt; ++kt) {
    const int k0 = kt * 64;
    f4v s[4];
#pragma unroll
    for (int nk = 0; nk < 4; ++nk) s[nk] = (f4v)0.f;
#pragma unroll
    for (int nk = 0; nk < 4; ++nk) {
      const unsigned short* kp = K + (rowbase + k0 + 16 * nk + lr) * HH + lg * 8;
      const s8v kf0 = *reinterpret_cast<const s8v*>(kp);
      const s8v kf1 = *reinterpret_cast<const s8v*>(kp + 32);
      s[nk] = __builtin_amdgcn_mfma_f32_16x16x32_bf16(qf[0], kf0, s[nk], 0, 0, 0);
      s[nk] = __builtin_amdgcn_mfma_f32_16x16x32_bf16(qf[1], kf1, s[nk], 0, 0, 0);
    }
    const bool diag = (kt == nt - 1);
#pragma unroll
    for (int nk = 0; nk < 4; ++nk) {
#pragma unroll
      for (int r = 0; r < 4; ++r) {
        float v = s[nk][r] * 0.125f;  // 1/sqrt(64)
        if (diag) {
          const int kk = k0 + 16 * nk + lr;
          const int qq = q0w + lg * 4 + r;
          if (kk > qq) v = -INFINITY;
        }
        s[nk][r] = v;
      }
    }
    float scl[4];
#pragma unroll
    for (int r = 0; r < 4; ++r) {
      float mx = fmaxf(fmaxf(s[0][r], s[1][r]), fmaxf(s[2][r], s[3][r]));
#pragma unroll
      for (int off = 1; off < 16; off <<= 1)
        mx = fmaxf(mx, __shfl_xor(mx, off));
      const float mnew = fmaxf(mrow[r], mx);
      scl[r] = __expf(mrow[r] - mnew);
      mrow[r] = mnew;
      float rs = 0.f;
#pragma unroll
      for (int nk = 0; nk < 4; ++nk) {
        const float p = __expf(s[nk][r] - mnew);
        s[nk][r] = p;
        rs += p;
      }
#pragma unroll
      for (int off = 1; off < 16; off <<= 1)
        rs += __shfl_xor(rs, off);
      lrow[r] = lrow[r] * scl[r] + rs;
    }
#pragma unroll
    for (int n = 0; n < 4; ++n)
#pragma unroll
      for (int r = 0; r < 4; ++r) o[n][r] *= scl[r];
    // P: D-layout -> LDS
#pragma unroll
    for (int nk = 0; nk < 4; ++nk)
#pragma unroll
      for (int r = 0; r < 4; ++r)
        pl[w][lg * 4 + r][16 * nk + lr] = f2bf(s[nk][r]);
    __syncthreads();
    // PV: A = P (from LDS), B = V^T rows (contiguous 16B)
#pragma unroll
    for (int kh = 0; kh < 2; ++kh) {
      const int pc = kh * 32 + lg * 8;
      const ushort4 plo = *reinterpret_cast<const ushort4*>(&pl[w][lr][pc]);
      const ushort4 phi = *reinterpret_cast<const ushort4*>(&pl[w][lr][pc + 4]);
      s8v pa;
      pa[0] = plo.x; pa[1] = plo.y; pa[2] = plo.z; pa[3] = plo.w;
      pa[4] = phi.x; pa[5] = phi.y; pa[6] = phi.z; pa[7] = phi.w;
#pragma unroll
      for (int n = 0; n < 4; ++n) {
        const s8v vf = *reinterpret_cast<const s8v*>(
            VT + ((size_t)b * HH + 16 * n + lr) * TT + k0 + kh * 32 + lg * 8);
        o[n] = __builtin_amdgcn_mfma_f32_16x16x32_bf16(pa, vf, o[n], 0, 0, 0);
      }
    }
    __syncthreads();
  }
#pragma unroll
  for (int n = 0; n < 4; ++n)
#pragma unroll
    for (int r = 0; r < 4; ++r) {
      const int qq = q0w + lg * 4 + r;
      out[(rowbase + qq) * HH + 16 * n + lr] = o[n][r] / lrow[r];
    }
}

extern "C" void kernel_launch(void* const* d_in, const int* in_sizes, int n_in,
                              void* d_out, int out_size, void* d_ws, size_t ws_size,
                              hipStream_t stream) {
  const float* x  = (const float*)d_in[0];
  const float* Wk = (const float*)d_in[1];
  const float* Wq = (const float*)d_in[2];
  const float* Wv = (const float*)d_in[3];
  float* out = (float*)d_out;

  unsigned short* ws = (unsigned short*)d_ws;
  unsigned short* Q  = ws;                           // BT*HH bf16
  unsigned short* K  = ws + (size_t)BT * HH;         // BT*HH bf16
  unsigned short* VT = ws + 2 * (size_t)BT * HH;     // B*HH*TT bf16
  unsigned short* WT = ws + 3 * (size_t)BT * HH;     // 3*64*1024 bf16

  conv_wt_kernel<<<768, 256, 0, stream>>>(Wq, Wk, Wv, WT);
  qkv_proj_mfma<<<256, 256, 0, stream>>>(x, WT, Q, K, VT);
  flash_attn_mfma<<<256, 256, 0, stream>>>(Q, K, VT, out);
}

// Round 3
// 110.281 us; speedup vs baseline: 9.5439x; 2.1342x over previous
//
#include <hip/hip_runtime.h>
#include <math.h>

#define BB 8
#define TT 2048
#define NE 1024
#define HH 64
#define BT (BB * TT)

typedef __attribute__((ext_vector_type(8))) short s8v;   // 8 x bf16 fragment
typedef __attribute__((ext_vector_type(4))) float f4v;   // 4 x f32 accum

__device__ inline unsigned short f2bf(float f) {
  union { float f; unsigned u; } v;
  v.f = f;
  unsigned r = (v.u + 0x7FFFu + ((v.u >> 16) & 1u)) >> 16;  // RNE
  return (unsigned short)r;
}

// ---------------------------------------------------------------------------
// Kernel 0: W [1024][64] f32 x3  ->  WT [192][1024] bf16 (rows: Q cols 0-63,
// K cols 64-127, V cols 128-191)
// ---------------------------------------------------------------------------
__global__ __launch_bounds__(256) void conv_wt_kernel(
    const float* __restrict__ Wq, const float* __restrict__ Wk,
    const float* __restrict__ Wv, unsigned short* __restrict__ WT) {
  const int idx = blockIdx.x * 256 + threadIdx.x;  // 0..3*65536-1
  const int m = idx >> 16;
  const int e = idx & 65535;
  const int n = e >> 6;
  const int h = e & 63;
  const float* W = (m == 0) ? Wq : (m == 1) ? Wk : Wv;
  WT[(size_t)m * 65536 + (size_t)h * NE + n] = f2bf(W[e]);
}

// ---------------------------------------------------------------------------
// Kernel 1: QKV projection, no-LDS MFMA.  512 blocks x 256 thr (4 waves).
//   wave w: wm=w&1 -> rows blk*32 + wm*16 (16 rows); wn=w>>1 -> cols wn*96
//   (6 x 16-col frags).  A direct from x (f32->bf16), B from L2-hot WT.
//   No barriers; unroll-4 keeps ~32 wave-loads in flight (Little's law).
// ---------------------------------------------------------------------------
__global__ __launch_bounds__(256, 2) void qkv_proj_mfma(
    const float* __restrict__ x, const unsigned short* __restrict__ WT,
    unsigned short* __restrict__ Q, unsigned short* __restrict__ K,
    unsigned short* __restrict__ VT) {
  const int tid = threadIdx.x;
  const int lane = tid & 63;
  const int w = tid >> 6;
  const int wm = w & 1, wn = w >> 1;
  const int lr = lane & 15, lg = lane >> 4;
  const int row0 = blockIdx.x * 32 + wm * 16;
  const int colbase = wn * 96;

  f4v acc[6];
#pragma unroll
  for (int c = 0; c < 6; ++c) acc[c] = (f4v)0.f;

  const float* __restrict__ xr = x + (size_t)(row0 + lr) * NE;
  const unsigned short* bp0 = WT + (size_t)(colbase + 0 * 16 + lr) * NE;
  const unsigned short* bp1 = WT + (size_t)(colbase + 1 * 16 + lr) * NE;
  const unsigned short* bp2 = WT + (size_t)(colbase + 2 * 16 + lr) * NE;
  const unsigned short* bp3 = WT + (size_t)(colbase + 3 * 16 + lr) * NE;
  const unsigned short* bp4 = WT + (size_t)(colbase + 4 * 16 + lr) * NE;
  const unsigned short* bp5 = WT + (size_t)(colbase + 5 * 16 + lr) * NE;

#pragma unroll 4
  for (int ks = 0; ks < NE; ks += 32) {
    const int k0 = ks + lg * 8;
    const float4 a0 = *reinterpret_cast<const float4*>(xr + k0);
    const float4 a1 = *reinterpret_cast<const float4*>(xr + k0 + 4);
    s8v a;
    a[0] = f2bf(a0.x); a[1] = f2bf(a0.y); a[2] = f2bf(a0.z); a[3] = f2bf(a0.w);
    a[4] = f2bf(a1.x); a[5] = f2bf(a1.y); a[6] = f2bf(a1.z); a[7] = f2bf(a1.w);
    const s8v b0 = *reinterpret_cast<const s8v*>(bp0 + k0);
    const s8v b1 = *reinterpret_cast<const s8v*>(bp1 + k0);
    const s8v b2 = *reinterpret_cast<const s8v*>(bp2 + k0);
    const s8v b3 = *reinterpret_cast<const s8v*>(bp3 + k0);
    const s8v b4 = *reinterpret_cast<const s8v*>(bp4 + k0);
    const s8v b5 = *reinterpret_cast<const s8v*>(bp5 + k0);
    acc[0] = __builtin_amdgcn_mfma_f32_16x16x32_bf16(a, b0, acc[0], 0, 0, 0);
    acc[1] = __builtin_amdgcn_mfma_f32_16x16x32_bf16(a, b1, acc[1], 0, 0, 0);
    acc[2] = __builtin_amdgcn_mfma_f32_16x16x32_bf16(a, b2, acc[2], 0, 0, 0);
    acc[3] = __builtin_amdgcn_mfma_f32_16x16x32_bf16(a, b3, acc[3], 0, 0, 0);
    acc[4] = __builtin_amdgcn_mfma_f32_16x16x32_bf16(a, b4, acc[4], 0, 0, 0);
    acc[5] = __builtin_amdgcn_mfma_f32_16x16x32_bf16(a, b5, acc[5], 0, 0, 0);
  }

#pragma unroll
  for (int c = 0; c < 6; ++c) {
    const int col = colbase + c * 16 + lr;
    const int m = col >> 6;   // uniform per (wn,c)
    const int h = col & 63;
#pragma unroll
    for (int r = 0; r < 4; ++r) {
      const int rr = row0 + lg * 4 + r;  // D: row=(lane>>4)*4+reg
      const unsigned short bv = f2bf(acc[c][r]);
      if (m == 0) {
        Q[(size_t)rr * HH + h] = bv;
      } else if (m == 1) {
        K[(size_t)rr * HH + h] = bv;
      } else {
        const int bb = rr >> 11, t = rr & (TT - 1);
        VT[((size_t)bb * HH + h) * TT + t] = bv;
      }
    }
  }
}

// ---------------------------------------------------------------------------
// Kernel 2: causal flash attention, in-block split-k.  1024 blocks x 4 waves.
//   block -> (batch b = bid&7 for XCD/L2 affinity, q-tile qt = bid>>3, 16 rows).
//   The qt's k-range (nt tiles of 64) is split across the 4 waves; each wave
//   runs an independent online-softmax flash loop (NO barriers in loop; the
//   P-LDS buffer is per-wave).  One barrier, then LDS combine of 4 partials.
// ---------------------------------------------------------------------------
__global__ __launch_bounds__(256, 4) void flash_attn_mfma(
    const unsigned short* __restrict__ Q, const unsigned short* __restrict__ K,
    const unsigned short* __restrict__ VT, float* __restrict__ out) {
  __shared__ unsigned short pl[4][16][72];
  __shared__ float ol[4][16][64];
  __shared__ float ml[4][16];
  __shared__ float ll[4][16];

  const int tid = threadIdx.x;
  const int lane = tid & 63;
  const int w = tid >> 6;
  const int lr = lane & 15;
  const int lg = lane >> 4;
  const int bid = blockIdx.x;
  const int b = bid & 7;
  const int qt = bid >> 3;          // 0..127
  const int q0 = qt * 16;
  const size_t rowbase = (size_t)b * TT;

  const int nt = (qt >> 2) + 1;     // k-tiles of 64 covering rows < q0+16
  const int base = nt >> 2, rem = nt & 3;
  const int t0 = w * base + (w < rem ? w : rem);
  const int cnt = base + (w < rem ? 1 : 0);

  const s8v qf0 = *reinterpret_cast<const s8v*>(
      Q + (rowbase + q0 + lr) * HH + lg * 8);
  const s8v qf1 = *reinterpret_cast<const s8v*>(
      Q + (rowbase + q0 + lr) * HH + 32 + lg * 8);

  f4v o[4];
#pragma unroll
  for (int n = 0; n < 4; ++n) o[n] = (f4v)0.f;
  float mrow[4], lrow[4];
#pragma unroll
  for (int r = 0; r < 4; ++r) { mrow[r] = -INFINITY; lrow[r] = 0.f; }

  for (int kt = t0; kt < t0 + cnt; ++kt) {
    const int k0 = kt * 64;
    f4v s[4];
#pragma unroll
    for (int nk = 0; nk < 4; ++nk) s[nk] = (f4v)0.f;
#pragma unroll
    for (int nk = 0; nk < 4; ++nk) {
      const unsigned short* kp = K + (rowbase + k0 + 16 * nk + lr) * HH + lg * 8;
      const s8v kf0 = *reinterpret_cast<const s8v*>(kp);
      const s8v kf1 = *reinterpret_cast<const s8v*>(kp + 32);
      s[nk] = __builtin_amdgcn_mfma_f32_16x16x32_bf16(qf0, kf0, s[nk], 0, 0, 0);
      s[nk] = __builtin_amdgcn_mfma_f32_16x16x32_bf16(qf1, kf1, s[nk], 0, 0, 0);
    }
    // hoist V loads: L2 latency hides under softmax
    s8v vfr[2][4];
#pragma unroll
    for (int kh = 0; kh < 2; ++kh)
#pragma unroll
      for (int n = 0; n < 4; ++n)
        vfr[kh][n] = *reinterpret_cast<const s8v*>(
            VT + ((size_t)b * HH + 16 * n + lr) * TT + k0 + kh * 32 + lg * 8);

    const bool diag = (kt == nt - 1);
#pragma unroll
    for (int nk = 0; nk < 4; ++nk) {
#pragma unroll
      for (int r = 0; r < 4; ++r) {
        float v = s[nk][r] * 0.125f;  // 1/sqrt(64)
        if (diag) {
          const int kk = k0 + 16 * nk + lr;
          const int qq = q0 + lg * 4 + r;
          if (kk > qq) v = -INFINITY;
        }
        s[nk][r] = v;
      }
    }
    float scl[4];
#pragma unroll
    for (int r = 0; r < 4; ++r) {
      float mx = fmaxf(fmaxf(s[0][r], s[1][r]), fmaxf(s[2][r], s[3][r]));
#pragma unroll
      for (int off = 1; off < 16; off <<= 1)
        mx = fmaxf(mx, __shfl_xor(mx, off));
      const float mnew = fmaxf(mrow[r], mx);
      scl[r] = __expf(mrow[r] - mnew);
      mrow[r] = mnew;
      float rs = 0.f;
#pragma unroll
      for (int nk = 0; nk < 4; ++nk) {
        const float p = __expf(s[nk][r] - mnew);
        s[nk][r] = p;
        rs += p;
      }
#pragma unroll
      for (int off = 1; off < 16; off <<= 1)
        rs += __shfl_xor(rs, off);
      lrow[r] = lrow[r] * scl[r] + rs;
    }
#pragma unroll
    for (int n = 0; n < 4; ++n)
#pragma unroll
      for (int r = 0; r < 4; ++r) o[n][r] *= scl[r];
    // P: D-layout -> per-wave LDS (no barrier needed)
#pragma unroll
    for (int nk = 0; nk < 4; ++nk)
#pragma unroll
      for (int r = 0; r < 4; ++r)
        pl[w][lg * 4 + r][16 * nk + lr] = f2bf(s[nk][r]);
    // PV
#pragma unroll
    for (int kh = 0; kh < 2; ++kh) {
      const int pc = kh * 32 + lg * 8;
      const ushort4 plo = *reinterpret_cast<const ushort4*>(&pl[w][lr][pc]);
      const ushort4 phi = *reinterpret_cast<const ushort4*>(&pl[w][lr][pc + 4]);
      s8v pa;
      pa[0] = plo.x; pa[1] = plo.y; pa[2] = plo.z; pa[3] = plo.w;
      pa[4] = phi.x; pa[5] = phi.y; pa[6] = phi.z; pa[7] = phi.w;
#pragma unroll
      for (int n = 0; n < 4; ++n)
        o[n] = __builtin_amdgcn_mfma_f32_16x16x32_bf16(pa, vfr[kh][n], o[n], 0, 0, 0);
    }
  }

  // publish per-wave partials
#pragma unroll
  for (int n = 0; n < 4; ++n)
#pragma unroll
    for (int r = 0; r < 4; ++r) ol[w][lg * 4 + r][16 * n + lr] = o[n][r];
  if (lr == 0) {
#pragma unroll
    for (int r = 0; r < 4; ++r) {
      ml[w][lg * 4 + r] = mrow[r];
      ll[w][lg * 4 + r] = lrow[r];
    }
  }
  __syncthreads();

  // combine: thread -> (row = tid>>4, 4 cols at (tid&15)*4)
  const int row = tid >> 4;
  const int c0 = (tid & 15) * 4;
  float m0 = ml[0][row], m1 = ml[1][row], m2 = ml[2][row], m3 = ml[3][row];
  const float ms = fmaxf(fmaxf(m0, m1), fmaxf(m2, m3));
  const float w0 = __expf(m0 - ms), w1 = __expf(m1 - ms);
  const float w2 = __expf(m2 - ms), w3 = __expf(m3 - ms);
  const float lsum = w0 * ll[0][row] + w1 * ll[1][row] +
                     w2 * ll[2][row] + w3 * ll[3][row];
  float4 osum;
  osum.x = w0 * ol[0][row][c0 + 0] + w1 * ol[1][row][c0 + 0] +
           w2 * ol[2][row][c0 + 0] + w3 * ol[3][row][c0 + 0];
  osum.y = w0 * ol[0][row][c0 + 1] + w1 * ol[1][row][c0 + 1] +
           w2 * ol[2][row][c0 + 1] + w3 * ol[3][row][c0 + 1];
  osum.z = w0 * ol[0][row][c0 + 2] + w1 * ol[1][row][c0 + 2] +
           w2 * ol[2][row][c0 + 2] + w3 * ol[3][row][c0 + 2];
  osum.w = w0 * ol[0][row][c0 + 3] + w1 * ol[1][row][c0 + 3] +
           w2 * ol[2][row][c0 + 3] + w3 * ol[3][row][c0 + 3];
  const float inv = 1.0f / lsum;
  float4 res;
  res.x = osum.x * inv; res.y = osum.y * inv;
  res.z = osum.z * inv; res.w = osum.w * inv;
  *reinterpret_cast<float4*>(out + (rowbase + q0 + row) * HH + c0) = res;
}

extern "C" void kernel_launch(void* const* d_in, const int* in_sizes, int n_in,
                              void* d_out, int out_size, void* d_ws, size_t ws_size,
                              hipStream_t stream) {
  const float* x  = (const float*)d_in[0];
  const float* Wk = (const float*)d_in[1];
  const float* Wq = (const float*)d_in[2];
  const float* Wv = (const float*)d_in[3];
  float* out = (float*)d_out;

  unsigned short* ws = (unsigned short*)d_ws;
  unsigned short* Q  = ws;                           // BT*HH bf16
  unsigned short* K  = ws + (size_t)BT * HH;         // BT*HH bf16
  unsigned short* VT = ws + 2 * (size_t)BT * HH;     // B*HH*TT bf16
  unsigned short* WT = ws + 3 * (size_t)BT * HH;     // 192*1024 bf16

  conv_wt_kernel<<<768, 256, 0, stream>>>(Wq, Wk, Wv, WT);
  qkv_proj_mfma<<<512, 256, 0, stream>>>(x, WT, Q, K, VT);
  flash_attn_mfma<<<1024, 256, 0, stream>>>(Q, K, VT, out);
}